// Round 10
// baseline (263.614 us; speedup 1.0000x reference)
//
#include <hip/hip_runtime.h>
#include <math.h>

// Problem constants (B, L, D, DH from the reference)
#define WS_B  4
#define WS_L  2048
#define WS_D  1024
#define WS_DH 2048
#define WS_M  (WS_B * WS_L)        // 8192 rows (B*L)
#define NCH   32                    // scan chunks per sequence
#define CHUNK (WS_L / NCH)          // 64 timesteps per chunk

typedef __attribute__((ext_vector_type(4))) float     f32x4;
typedef _Float16 f16x8 __attribute__((ext_vector_type(8)));   // MFMA A/B frag (4 VGPRs)
typedef _Float16 f16x4 __attribute__((ext_vector_type(4)));

#define GLDS(gptr, lptr) \
    __builtin_amdgcn_global_load_lds( \
        (const __attribute__((address_space(1))) unsigned int*)(gptr), \
        (__attribute__((address_space(3))) unsigned int*)(lptr), 16, 0, 0)

// ---- pack fp32 row-major [R,K] -> fp16 tile-major P[rb][kc][r][8] ----
// Packed layout mirrors the GEMM's LDS destination: staging wave-instrs read
// 64 lanes x 16B CONTIGUOUS (8 cache lines, not 64) — the R8 2x win.
__global__ void pack_f16(const float* __restrict__ src, _Float16* __restrict__ dst,
                         int K, int k8log, int nChunks) {
    int chunk = blockIdx.x * 256 + threadIdx.x;
    if (chunk >= nChunks) return;
    int r    = chunk & 127;
    int rest = chunk >> 7;
    int K8m  = (1 << k8log) - 1;
    int kc   = rest & K8m;
    int rb   = rest >> k8log;
    const float* s = src + ((size_t)(rb * 128 + r) * K + kc * 8);
    f32x4 v0 = *(const f32x4*)s;
    f32x4 v1 = *(const f32x4*)(s + 4);
    f16x8 h;
#pragma unroll
    for (int k = 0; k < 4; ++k) { h[k] = (_Float16)v0[k]; h[4 + k] = (_Float16)v1[k]; }
    *(f16x8*)(dst + (size_t)chunk * 8) = h;   // consecutive threads -> consecutive 16B
}

// ---- unified packed fp16 GEMM:  C[m,n] = sum_k A[m,k]*B[n,k] + bias[n] ----
// 128x128 tile, BK=32. R10: depth-4 LDS ring + partial vmcnt drain + raw s_barrier.
// Steady-state sync per kstep: each wave waits vmcnt(8) (drains ONLY its own 4
// slab-k loads; slabs k+1,k+2 stay in flight), s_barrier joins the waves (every
// wave drained its own slab-k contribution -> slab k fully in LDS), then slab
// k+3 is issued into the slot consumed at kstep k-1 (safe: all waves passed the
// barrier after consuming it). Loads get ~3 kstep-periods to land instead of 1 —
// removes the load-latency exposure that held P at 1129 cyc/CU-kstep in R9
// (MfmaUtil 22%, staging only 14.5 B/cyc vs 56 B/cyc L2 feed).
template<int K8, int LDC>
__global__ __launch_bounds__(256, 2)
void gemm_f16_packed(const _Float16* __restrict__ A, const _Float16* __restrict__ B,
                     const float* __restrict__ bias, float* __restrict__ C)
{
    constexpr int NK = K8 / 4;                     // ksteps (BK=32 = 4 k-chunks)
    __shared__ alignas(16) _Float16 sA[4][4][128][8];   // 4-slot ring, 32 KB
    __shared__ alignas(16) _Float16 sB[4][4][128][8];   // 32 KB

    const int tid  = threadIdx.x;
    const int lane = tid & 63;
    const int wave = tid >> 6;
    const int wm   = (wave >> 1) * 64;
    const int wn   = (wave & 1) * 64;
    const int m15  = lane & 15;
    const int q    = lane >> 4;

    const int bm = blockIdx.x;
    const int bn = blockIdx.y;

    f32x4 acc[4][4] = {};

    // stage slab k (4 k-chunks) into ring slot; 4 GLDS per thread per call
    auto stage = [&](int k, int slot) {
        int kc0 = k * 4;
#pragma unroll
        for (int i = 0; i < 2; ++i) {
            int c   = i * 256 + tid;     // 512 chunks per matrix
            int row = c & 127;
            int kq  = c >> 7;            // wave-uniform
            size_t ac = ((size_t)(bm * K8 + kc0 + kq) * 128 + row) * 8;
            size_t bc = ((size_t)(bn * K8 + kc0 + kq) * 128 + row) * 8;
            GLDS(A + ac, &sA[slot][kq][row][0]);   // 64 lanes x 16B contiguous
            GLDS(B + bc, &sB[slot][kq][row][0]);
        }
    };

    stage(0, 0);
    stage(1, 1);
    stage(2, 2);

    for (int k = 0; k < NK; ++k) {
        // drain own slab-k loads only; keep deeper prefetches in flight
        if (k < NK - 2)       { __asm__ volatile("s_waitcnt vmcnt(8)" ::: "memory"); }
        else if (k == NK - 2) { __asm__ volatile("s_waitcnt vmcnt(4)" ::: "memory"); }
        else                  { __asm__ volatile("s_waitcnt vmcnt(0)" ::: "memory"); }
        __asm__ volatile("s_barrier" ::: "memory");
        if (k + 3 < NK) stage(k + 3, (k + 3) & 3);

        const int slot = k & 3;
        f16x8 af[4], bf[4];
#pragma unroll
        for (int i = 0; i < 4; ++i) {
            af[i] = *(const f16x8*)&sA[slot][q][wm + i * 16 + m15][0];
            bf[i] = *(const f16x8*)&sB[slot][q][wn + i * 16 + m15][0];
        }
#pragma unroll
        for (int i = 0; i < 4; ++i)
#pragma unroll
            for (int j = 0; j < 4; ++j)
                acc[i][j] = __builtin_amdgcn_mfma_f32_16x16x32_f16(af[i], bf[j], acc[i][j], 0, 0, 0);
    }

    const int r4 = (lane >> 4) * 4;   // C/D: col=lane&15, row=(lane>>4)*4+reg (m89)
#pragma unroll
    for (int j = 0; j < 4; ++j) {
        int col = bn * 128 + wn + j * 16 + m15;
        float bv = bias[col];
#pragma unroll
        for (int i = 0; i < 4; ++i) {
            int row0 = bm * 128 + wm + i * 16 + r4;
#pragma unroll
            for (int r = 0; r < 4; ++r)
                C[(size_t)(row0 + r) * LDC + col] = acc[i][j][r] + bv;
        }
    }
}

// ---- scan: U[t] = p*U[t-1] + p0*h[t], U[-1]=last;  z[t]=Re(U[t]); y=silu(z) ----
__device__ inline void compute_p(const float* __restrict__ phazor, int c, float& pre, float& pim) {
    float zr = phazor[2 * c], zi = phazor[2 * c + 1];
    float pa = sqrtf(zr * zr + zi * zi);
    float sc = expf(-pa) / pa;       // unit phase * exp(-|p|) magnitude
    pre = zr * sc;
    pim = zi * sc;
}

// phase 1: per-chunk local scan (init 0), write chunk-end state
__global__ void scan_local(const float* __restrict__ h, const float* __restrict__ phazor,
                           const float* __restrict__ phazor_init, float* __restrict__ Uend) {
    int idx = blockIdx.x * blockDim.x + threadIdx.x;      // [0, B*NCH*DH)
    if (idx >= WS_B * NCH * WS_DH) return;
    int c  = idx & (WS_DH - 1);
    int bj = idx >> 11;
    int j  = bj & (NCH - 1);
    int b  = bj >> 5;
    float pre, pim;
    compute_p(phazor, c, pre, pim);
    float p0r = phazor_init[2 * c], p0i = phazor_init[2 * c + 1];
    const float* hp = h + ((size_t)(b * WS_L + j * CHUNK)) * WS_DH + c;
    float ur = 0.f, ui = 0.f;
    for (int t = 0; t < CHUNK; t += 8) {
        float hv[8];
#pragma unroll
        for (int u = 0; u < 8; ++u) hv[u] = hp[(size_t)(t + u) * WS_DH];
#pragma unroll
        for (int u = 0; u < 8; ++u) {
            float nr = fmaf(pre, ur, fmaf(-pim, ui, p0r * hv[u]));
            float ni = fmaf(pre, ui, fmaf( pim, ur, p0i * hv[u]));
            ur = nr; ui = ni;
        }
    }
    Uend[2 * idx] = ur;
    Uend[2 * idx + 1] = ui;
}

// phase 2: serial combine over chunks; carry[j] = full state entering chunk j
__global__ void scan_carry(const float* __restrict__ Uend, float* __restrict__ carry,
                           const float* __restrict__ phazor,
                           const float* __restrict__ last_re, const float* __restrict__ last_im) {
    int idx = blockIdx.x * blockDim.x + threadIdx.x;      // [0, B*DH)
    if (idx >= WS_B * WS_DH) return;
    int c = idx & (WS_DH - 1);
    int b = idx >> 11;
    float pre, pim;
    compute_p(phazor, c, pre, pim);
    float qr = pre, qi = pim;                              // p^CHUNK via 6 squarings (CHUNK=64)
#pragma unroll
    for (int s = 0; s < 6; ++s) {
        float nr = qr * qr - qi * qi;
        qi = 2.f * qr * qi;
        qr = nr;
    }
    float ur = last_re[idx], ui = last_im[idx];            // U[-1] = last
    for (int j = 0; j < NCH; ++j) {
        int o = (b * NCH + j) * WS_DH + c;
        carry[2 * o] = ur;
        carry[2 * o + 1] = ui;
        float Lr = Uend[2 * o], Li = Uend[2 * o + 1];
        float nr = fmaf(qr, ur, fmaf(-qi, ui, Lr));
        float ni = fmaf(qr, ui, fmaf( qi, ur, Li));
        ur = nr; ui = ni;
    }
}

// phase 3: re-scan from carry, silu, write y (fp16, single-rounded) DIRECTLY in
// packed tile-major layout P[rb][kc][r][8] (K8=256).
__global__ void scan_apply(const float* __restrict__ h, const float* __restrict__ phazor,
                           const float* __restrict__ phazor_init, const float* __restrict__ carry,
                           _Float16* __restrict__ yh) {
    int idx = blockIdx.x * blockDim.x + threadIdx.x;
    if (idx >= WS_B * NCH * WS_DH) return;
    int c  = idx & (WS_DH - 1);
    int bj = idx >> 11;
    int j  = bj & (NCH - 1);
    int b  = bj >> 5;
    float pre, pim;
    compute_p(phazor, c, pre, pim);
    float p0r = phazor_init[2 * c], p0i = phazor_init[2 * c + 1];
    float ur = carry[2 * idx], ui = carry[2 * idx + 1];
    const int row0 = b * WS_L + j * CHUNK;
    const float* hp = h + (size_t)row0 * WS_DH + c;
    const int chi = c >> 3, clo = c & 7;                   // packed column split
    for (int t = 0; t < CHUNK; t += 8) {
        float hv[8];
#pragma unroll
        for (int u = 0; u < 8; ++u) hv[u] = hp[(size_t)(t + u) * WS_DH];
#pragma unroll
        for (int u = 0; u < 8; ++u) {
            float nr = fmaf(pre, ur, fmaf(-pim, ui, p0r * hv[u]));
            float ni = fmaf(pre, ui, fmaf( pim, ur, p0i * hv[u]));
            ur = nr; ui = ni;
            float z  = ur;                                  // Re(U[t])
            float yv = z / (1.f + expf(-z));                // silu
            int row = row0 + t + u;
            size_t o = (((size_t)(row >> 7) * 256 + chi) * 128 + (row & 127)) * 8 + clo;
            yh[o] = (_Float16)yv;
        }
    }
}

extern "C" void kernel_launch(void* const* d_in, const int* in_sizes, int n_in,
                              void* d_out, int out_size, void* d_ws, size_t ws_size,
                              hipStream_t stream)
{
    const float* x       = (const float*)d_in[0];
    const float* W_in    = (const float*)d_in[1];
    const float* b_in    = (const float*)d_in[2];
    const float* W_out   = (const float*)d_in[3];
    const float* b_out   = (const float*)d_in[4];
    const float* phazor  = (const float*)d_in[5];
    const float* ph_init = (const float*)d_in[6];
    const float* last_re = (const float*)d_in[7];
    const float* last_im = (const float*)d_in[8];
    float* out = (float*)d_out;

    // workspace carve-up (~124 MB)
    char* ws = (char*)d_ws;
    size_t off = 0;
    auto alloc = [&](size_t bytes) {
        char* p = ws + off;
        off += (bytes + 255) & ~(size_t)255;
        return p;
    };
    _Float16* xp    = (_Float16*)alloc((size_t)WS_M * WS_D * 2);     // 16 MB packed
    _Float16* w1p   = (_Float16*)alloc((size_t)WS_DH * WS_D * 2);    //  4 MB packed
    _Float16* w2p   = (_Float16*)alloc((size_t)WS_D * WS_DH * 2);    //  4 MB packed
    float*    h     = (float*)alloc((size_t)WS_M * WS_DH * 4);       // 64 MB
    _Float16* yhp   = (_Float16*)alloc((size_t)WS_M * WS_DH * 2);    // 32 MB packed
    float*    Uend  = (float*)alloc((size_t)WS_B * NCH * WS_DH * 2 * 4);
    float*    carry = (float*)alloc((size_t)WS_B * NCH * WS_DH * 2 * 4);

    // 1) pack inputs to fp16 tile-major
    {
        int n = WS_M * WS_D / 8;      // x: R=8192, K=1024, K8=128 (log 7)
        pack_f16<<<dim3((n + 255) / 256), dim3(256), 0, stream>>>(x, xp, WS_D, 7, n);
        n = WS_DH * WS_D / 8;         // W_in: R=2048, K=1024
        pack_f16<<<dim3((n + 255) / 256), dim3(256), 0, stream>>>(W_in, w1p, WS_D, 7, n);
        n = WS_D * WS_DH / 8;         // W_out: R=1024, K=2048, K8=256 (log 8)
        pack_f16<<<dim3((n + 255) / 256), dim3(256), 0, stream>>>(W_out, w2p, WS_DH, 8, n);
    }

    // 2) h = x @ W_in^T + b_in   [8192, 2048], grid 64x16 = 1024 blocks
    {
        dim3 g(WS_M / 128, WS_DH / 128);
        gemm_f16_packed<WS_D / 8, WS_DH><<<g, dim3(256), 0, stream>>>(xp, w1p, b_in, h);
    }

    // 3) chunked complex scan + silu -> yh (fp16, packed)
    {
        int total = WS_B * NCH * WS_DH;
        scan_local<<<dim3(total / 256), dim3(256), 0, stream>>>(h, phazor, ph_init, Uend);
        scan_carry<<<dim3(WS_B * WS_DH / 256), dim3(256), 0, stream>>>(Uend, carry, phazor,
                                                                       last_re, last_im);
        scan_apply<<<dim3(total / 256), dim3(256), 0, stream>>>(h, phazor, ph_init, carry, yhp);
    }

    // 4) out = yh @ W_out^T + b_out, K=2048, grid 64x8 = 512 blocks
    {
        dim3 g(WS_M / 128, WS_D / 128);
        gemm_f16_packed<WS_DH / 8, WS_D><<<g, dim3(256), 0, stream>>>(yhp, w2p, b_out, out);
    }
}